// Round 1
// baseline (817.802 us; speedup 1.0000x reference)
//
#include <hip/hip_runtime.h>
#include <hip/hip_bf16.h>

// Problem constants
#define T_TOK 4096
#define DDIM  2048
#define IDIM  1024
#define NEXP  8
#define NPAIR 8192   // T_TOK * top_k

typedef unsigned short u16;
typedef __bf16 bf16x8 __attribute__((ext_vector_type(8)));
typedef float  f32x4  __attribute__((ext_vector_type(4)));
typedef unsigned short u16x4 __attribute__((ext_vector_type(4)));

__device__ __forceinline__ u16 f2bf(float f) {
  union { float f; unsigned u; } v; v.f = f;
  unsigned r = v.u + 0x7fffu + ((v.u >> 16) & 1u);   // RNE
  return (u16)(r >> 16);
}

// async global->LDS, 16B per lane; LDS dest must be wave-uniform base (+lane*16 by HW)
__device__ __forceinline__ void gll16(const void* g, void* l) {
  __builtin_amdgcn_global_load_lds(
      (__attribute__((address_space(1))) void*)(g),
      (__attribute__((address_space(3))) void*)(l),
      16, 0, 0);
}

// ---------------- router: logits = x @ rw (fp64 accum), top-2, sigmoid ----------------
__global__ __launch_bounds__(256)
void router_kernel(const float* __restrict__ x, const float* __restrict__ rw,
                   int* __restrict__ top_idx, float* __restrict__ top_w,
                   int* __restrict__ counts) {
  int t = blockIdx.x;
  int tid = threadIdx.x;
  int lane = tid & 63, wave = tid >> 6;
  const float* xr = x + (size_t)t * DDIM;
  double acc[NEXP];
#pragma unroll
  for (int e = 0; e < NEXP; ++e) acc[e] = 0.0;
  for (int d = tid; d < DDIM; d += 256) {
    double xv = (double)xr[d];
    const float* r = rw + (size_t)d * NEXP;
#pragma unroll
    for (int e = 0; e < NEXP; ++e) acc[e] += xv * (double)r[e];
  }
  __shared__ double wred[4][NEXP];
#pragma unroll
  for (int e = 0; e < NEXP; ++e) {
    double v = acc[e];
    for (int s = 32; s > 0; s >>= 1) v += __shfl_down(v, s);
    if (lane == 0) wred[wave][e] = v;
  }
  __syncthreads();
  if (tid == 0) {
    float lg[NEXP];
#pragma unroll
    for (int e = 0; e < NEXP; ++e)
      lg[e] = (float)(wred[0][e] + wred[1][e] + wred[2][e] + wred[3][e]);
    int e0 = 0; float v0 = lg[0];
    for (int e = 1; e < NEXP; ++e) if (lg[e] > v0) { v0 = lg[e]; e0 = e; }
    int e1 = -1; float v1 = -3.4e38f;
    for (int e = 0; e < NEXP; ++e) if (e != e0 && lg[e] > v1) { v1 = lg[e]; e1 = e; }
    float p0 = 1.0f / (1.0f + __expf(-v0));
    float p1 = 1.0f / (1.0f + __expf(-v1));
    top_idx[t * 2 + 0] = e0; top_idx[t * 2 + 1] = e1;
    top_w[t * 2 + 0] = p0;  top_w[t * 2 + 1] = p1;
    atomicAdd(&counts[e0], 1);
    atomicAdd(&counts[e1], 1);
  }
}

__global__ void init_kernel(int* counts) {
  if (threadIdx.x < NEXP) counts[threadIdx.x] = 0;
}

// prefix sum over 8 experts + build row-tile table (fixed worst-case 71 tiles)
__global__ void offsets_kernel(const int* __restrict__ counts, int* __restrict__ offs,
                               int* __restrict__ fill, int* __restrict__ tab,
                               int* __restrict__ ntl) {
  if (blockIdx.x == 0 && threadIdx.x == 0) {
    int off = 0, nt = 0;
    for (int e = 0; e < NEXP; ++e) {
      offs[e] = off;
      int c = counts[e];
      int tb = (c + 127) >> 7;
      for (int t = 0; t < tb; ++t) tab[nt++] = (e << 16) | t;
      off += c;
      fill[e] = 0;
    }
    offs[NEXP] = off;
    *ntl = nt;
    for (int i = nt; i < 128; ++i) tab[i] = 0;
  }
}

__global__ __launch_bounds__(256)
void scatter_kernel(const int* __restrict__ top_idx, const float* __restrict__ top_w,
                    const int* __restrict__ offs, int* __restrict__ fill,
                    int* __restrict__ tlist, float* __restrict__ pw) {
  int t = blockIdx.x * blockDim.x + threadIdx.x;
  if (t >= T_TOK) return;
#pragma unroll
  for (int k = 0; k < 2; ++k) {
    int e = top_idx[t * 2 + k];
    float w = top_w[t * 2 + k];
    int pos = offs[e] + atomicAdd(&fill[e], 1);
    tlist[pos] = t;
    pw[pos] = w;
  }
}

// ---------------- fp32 -> bf16 convert of x ----------------
__global__ __launch_bounds__(256)
void cvt_x_kernel(const float* __restrict__ in, u16* __restrict__ out) {
  size_t i = ((size_t)blockIdx.x * blockDim.x + threadIdx.x) * 4;
  float4 v = *(const float4*)(in + i);
  u16x4 o;
  o.x = f2bf(v.x); o.y = f2bf(v.y); o.z = f2bf(v.z); o.w = f2bf(v.w);
  *(u16x4*)(out + i) = o;
}

// ---------------- weight transposes (fp32 [K][N] -> bf16 [N][K]) ----------------
// gate_up_w [E][D][2I] -> gut [E][2I][D], rows interleaved: out[e][2i+s][d] = in[e][d][s*I+i]
__global__ __launch_bounds__(256)
void t_gateup_kernel(const float* __restrict__ in, u16* __restrict__ out) {
  __shared__ float tile[32][33];
  int z = blockIdx.z, e = z >> 1, s = z & 1;
  int d0 = blockIdx.x * 32, i0 = blockIdx.y * 32;
  int tx = threadIdx.x, ty = threadIdx.y;
  const float* ib = in + ((size_t)e * DDIM + d0) * (2 * IDIM) + (size_t)s * IDIM + i0;
#pragma unroll
  for (int r = 0; r < 4; ++r)
    tile[ty * 4 + r][tx] = ib[(size_t)(ty * 4 + r) * (2 * IDIM) + tx];
  __syncthreads();
  u16* ob = out + (size_t)e * (2 * IDIM) * DDIM;
#pragma unroll
  for (int r = 0; r < 4; ++r) {
    int c = ty * 4 + r;
    int nrow = 2 * (i0 + c) + s;
    ob[(size_t)nrow * DDIM + d0 + tx] = f2bf(tile[tx][c]);
  }
}

// shared gate/up [D][I] x2 -> sgut [2I][D] interleaved
__global__ __launch_bounds__(256)
void t_sgu_kernel(const float* __restrict__ sg, const float* __restrict__ su,
                  u16* __restrict__ out) {
  __shared__ float tile[32][33];
  int s = blockIdx.z;
  const float* in = s ? su : sg;
  int d0 = blockIdx.x * 32, i0 = blockIdx.y * 32;
  int tx = threadIdx.x, ty = threadIdx.y;
#pragma unroll
  for (int r = 0; r < 4; ++r)
    tile[ty * 4 + r][tx] = in[(size_t)(d0 + ty * 4 + r) * IDIM + i0 + tx];
  __syncthreads();
#pragma unroll
  for (int r = 0; r < 4; ++r) {
    int c = ty * 4 + r;
    int nrow = 2 * (i0 + c) + s;
    out[(size_t)nrow * DDIM + d0 + tx] = f2bf(tile[tx][c]);
  }
}

// down [E][I][D] -> dwt [E][D][I]  (also used for shared_down with gridDim.z==1)
__global__ __launch_bounds__(256)
void t_down_kernel(const float* __restrict__ in, u16* __restrict__ out) {
  __shared__ float tile[32][33];
  int e = blockIdx.z;
  int i0 = blockIdx.x * 32, d0 = blockIdx.y * 32;
  int tx = threadIdx.x, ty = threadIdx.y;
  const float* ib = in + (size_t)e * IDIM * DDIM;
  u16* ob = out + (size_t)e * IDIM * DDIM;
#pragma unroll
  for (int r = 0; r < 4; ++r)
    tile[ty * 4 + r][tx] = ib[(size_t)(i0 + ty * 4 + r) * DDIM + d0 + tx];
  __syncthreads();
#pragma unroll
  for (int r = 0; r < 4; ++r) {
    int c = ty * 4 + r;
    ob[(size_t)(d0 + c) * IDIM + i0 + tx] = f2bf(tile[tx][c]);
  }
}

// ---------------- main tiled GEMM (m97 structure) ----------------
// A [M][Kdim] bf16 (row stride Kdim), Bt [N=2048][Kdim] bf16 (expert slab = 2048*Kdim)
// GATEUP epilogue: p-scale pre-silu, shuffle-combine interleaved gate/up -> bf16 h
// DOWN epilogue:  plain store (shared, initializes out) or gather-atomicAdd (expert)
template <bool EXPERT, bool GATEUP>
__global__ __launch_bounds__(256)
void gemm_kernel(const u16* __restrict__ A, const u16* __restrict__ Bt,
                 float* __restrict__ outp, u16* __restrict__ hout,
                 const int* __restrict__ tab, const int* __restrict__ ntl,
                 const int* __restrict__ offs, const int* __restrict__ tlist,
                 const float* __restrict__ pw, int Kdim) {
  constexpr int BM = 128, BN = 128, BK = 32;
  __shared__ alignas(16) u16 Asm[BM * BK];
  __shared__ alignas(16) u16 Bsm[BN * BK];

  int bx = blockIdx.x, by = blockIdx.y;
  int m0, mcnt, seg = 0, e = 0;
  if constexpr (EXPERT) {
    int nt = *ntl;
    if (bx >= nt) return;
    int tt = tab[bx];
    e = tt >> 16;
    int rb = tt & 0xffff;
    seg = offs[e];
    mcnt = offs[e + 1] - seg;
    m0 = rb * BM;
  } else {
    m0 = bx * BM;
    mcnt = T_TOK;
  }
  int n0 = by * BN;
  const u16* Bte = Bt + (size_t)e * 2048 * (size_t)Kdim + (size_t)n0 * Kdim;

  int tid = threadIdx.x;
  int lane = tid & 63, wave = tid >> 6;
  int wm = (wave & 1) * 64, wn = (wave >> 1) * 64;

  int sr0 = wave * 16 + (lane >> 2);  // staged row (this thread), issue 0
  int colb = (lane & 3) * 8;          // element offset of this thread's 16B chunk

  const u16 *ap0, *ap1;
  {
    int g0 = m0 + sr0, g1 = m0 + sr0 + 64;
    if constexpr (EXPERT) {
      if (g0 > mcnt - 1) g0 = mcnt - 1;
      if (g1 > mcnt - 1) g1 = mcnt - 1;
      if constexpr (GATEUP) {
        ap0 = A + (size_t)tlist[seg + g0] * Kdim;
        ap1 = A + (size_t)tlist[seg + g1] * Kdim;
      } else {
        ap0 = A + (size_t)(seg + g0) * Kdim;
        ap1 = A + (size_t)(seg + g1) * Kdim;
      }
    } else {
      ap0 = A + (size_t)g0 * Kdim;
      ap1 = A + (size_t)g1 * Kdim;
    }
  }
  const u16* bp0 = Bte + (size_t)sr0 * Kdim;
  const u16* bp1 = Bte + (size_t)(sr0 + 64) * Kdim;

  u16* As0 = Asm + (wave * 16) * BK;
  u16* As1 = Asm + (64 + wave * 16) * BK;
  u16* Bs0 = Bsm + (wave * 16) * BK;
  u16* Bs1 = Bsm + (64 + wave * 16) * BK;

  f32x4 acc[4][4] = {};

  for (int k0 = 0; k0 < Kdim; k0 += BK) {
    gll16(ap0 + k0 + colb, As0);
    gll16(ap1 + k0 + colb, As1);
    gll16(bp0 + k0 + colb, Bs0);
    gll16(bp1 + k0 + colb, Bs1);
    asm volatile("s_waitcnt vmcnt(0)" ::: "memory");
    __syncthreads();

    int kq = (lane >> 4) * 8;
    bf16x8 af[4], bfr[4];
#pragma unroll
    for (int t = 0; t < 4; ++t) {
      af[t]  = *(const bf16x8*)(Asm + (size_t)(wm + t * 16 + (lane & 15)) * BK + kq);
      bfr[t] = *(const bf16x8*)(Bsm + (size_t)(wn + t * 16 + (lane & 15)) * BK + kq);
    }
#pragma unroll
    for (int tm = 0; tm < 4; ++tm)
#pragma unroll
      for (int tn = 0; tn < 4; ++tn)
        acc[tm][tn] = __builtin_amdgcn_mfma_f32_16x16x32_bf16(af[tm], bfr[tn], acc[tm][tn], 0, 0, 0);
    __syncthreads();
  }

  // epilogue: C/D layout col = lane&15 (N), row = (lane>>4)*4 + r (M)
  int cn = lane & 15;
  int rq = (lane >> 4) * 4;

  if constexpr (GATEUP) {
#pragma unroll
    for (int tm = 0; tm < 4; ++tm) {
#pragma unroll
      for (int r = 0; r < 4; ++r) {
        int mloc = wm + tm * 16 + rq + r;
        int mg = m0 + mloc;
        bool valid;
        float p;
        if constexpr (EXPERT) {
          valid = (mg < mcnt);
          int pi = seg + mg; if (pi > NPAIR - 1) pi = NPAIR - 1;
          p = pw[pi];
          if (!valid) p = 0.0f;
        } else { valid = true; p = 1.0f; }
#pragma unroll
        for (int tn = 0; tn < 4; ++tn) {
          float v = acc[tm][tn][r] * p;       // p applied PRE-silu (matches reference)
          float o = __shfl_xor(v, 1);         // partner column (gate<->up)
          if (!(cn & 1) && valid) {
            float g = v, u = o;
            float h = (g / (1.0f + __expf(-g))) * u;   // silu(g)*u
            int nbase = n0 + wn + tn * 16;
            int i = (nbase >> 1) + (cn >> 1);
            size_t row = EXPERT ? (size_t)(seg + mg) : (size_t)mg;
            hout[row * IDIM + i] = f2bf(h);
          }
        }
      }
    }
  } else {
#pragma unroll
    for (int tm = 0; tm < 4; ++tm) {
#pragma unroll
      for (int r = 0; r < 4; ++r) {
        int mloc = wm + tm * 16 + rq + r;
        int mg = m0 + mloc;
        if constexpr (EXPERT) {
          if (mg < mcnt) {
            int tok = tlist[seg + mg];
#pragma unroll
            for (int tn = 0; tn < 4; ++tn) {
              int n = n0 + wn + tn * 16 + cn;
              atomicAdd(&outp[(size_t)tok * DDIM + n], acc[tm][tn][r]);
            }
          }
        } else {
#pragma unroll
          for (int tn = 0; tn < 4; ++tn) {
            int n = n0 + wn + tn * 16 + cn;
            outp[(size_t)mg * DDIM + n] = acc[tm][tn][r];
          }
        }
      }
    }
  }
}

// ---------------- launch ----------------
extern "C" void kernel_launch(void* const* d_in, const int* in_sizes, int n_in,
                              void* d_out, int out_size, void* d_ws, size_t ws_size,
                              hipStream_t stream) {
  const float* x   = (const float*)d_in[0];
  const float* rw  = (const float*)d_in[1];
  const float* guw = (const float*)d_in[2];
  const float* dw  = (const float*)d_in[3];
  const float* sgw = (const float*)d_in[4];
  const float* suw = (const float*)d_in[5];
  const float* sdw = (const float*)d_in[6];
  float* outp = (float*)d_out;
  (void)in_sizes; (void)n_in; (void)out_size; (void)ws_size;

  char* ws = (char*)d_ws;
  size_t off = 0;
  auto alloc = [&](size_t bytes) -> void* {
    void* p = ws + off;
    off += (bytes + 255) & ~(size_t)255;
    return p;
  };
  u16* xb    = (u16*)alloc((size_t)T_TOK * DDIM * 2);        // 16.8 MB
  u16* gut   = (u16*)alloc((size_t)NEXP * 2 * IDIM * DDIM * 2); // 67.1 MB
  u16* dwt   = (u16*)alloc((size_t)NEXP * DDIM * IDIM * 2);  // 33.6 MB
  u16* sgut  = (u16*)alloc((size_t)2 * IDIM * DDIM * 2);     // 8.4 MB
  u16* sdt   = (u16*)alloc((size_t)DDIM * IDIM * 2);         // 4.2 MB
  u16* hs    = (u16*)alloc((size_t)T_TOK * IDIM * 2);        // 8.4 MB
  u16* he    = (u16*)alloc((size_t)NPAIR * IDIM * 2);        // 16.8 MB
  int* top_idx = (int*)alloc(T_TOK * 2 * 4);
  float* top_w = (float*)alloc(T_TOK * 2 * 4);
  int* counts  = (int*)alloc(NEXP * 4);
  int* offs    = (int*)alloc((NEXP + 1) * 4);
  int* fill    = (int*)alloc(NEXP * 4);
  int* tab     = (int*)alloc(128 * 4);
  int* ntl     = (int*)alloc(4);
  int* tlist   = (int*)alloc(NPAIR * 4);
  float* pw    = (float*)alloc(NPAIR * 4);

  // routing
  init_kernel<<<dim3(1), dim3(64), 0, stream>>>(counts);
  router_kernel<<<dim3(T_TOK), dim3(256), 0, stream>>>(x, rw, top_idx, top_w, counts);
  offsets_kernel<<<dim3(1), dim3(1), 0, stream>>>(counts, offs, fill, tab, ntl);
  scatter_kernel<<<dim3(16), dim3(256), 0, stream>>>(top_idx, top_w, offs, fill, tlist, pw);

  // fp32 -> bf16 (+transpose) pre-pass
  cvt_x_kernel<<<dim3(8192), dim3(256), 0, stream>>>(x, xb);
  t_gateup_kernel<<<dim3(64, 32, 16), dim3(32, 8), 0, stream>>>(guw, gut);
  t_down_kernel<<<dim3(32, 64, 8), dim3(32, 8), 0, stream>>>(dw, dwt);
  t_sgu_kernel<<<dim3(64, 32, 2), dim3(32, 8), 0, stream>>>(sgw, suw, sgut);
  t_down_kernel<<<dim3(32, 64, 1), dim3(32, 8), 0, stream>>>(sdw, sdt);

  // shared expert: hs = silu(x@sg)*(x@su); out = hs @ sd   (out fully written here)
  gemm_kernel<false, true><<<dim3(32, 16), dim3(256), 0, stream>>>(
      xb, sgut, nullptr, hs, nullptr, nullptr, nullptr, nullptr, nullptr, DDIM);
  gemm_kernel<false, false><<<dim3(32, 16), dim3(256), 0, stream>>>(
      hs, sdt, outp, nullptr, nullptr, nullptr, nullptr, nullptr, nullptr, IDIM);

  // routed experts: he = silu(p*(x@Wg))*(p*(x@Wu)); out += he @ Wd (atomic scatter)
  gemm_kernel<true, true><<<dim3(71, 16), dim3(256), 0, stream>>>(
      xb, gut, nullptr, he, tab, ntl, offs, tlist, pw, DDIM);
  gemm_kernel<true, false><<<dim3(71, 16), dim3(256), 0, stream>>>(
      he, dwt, outp, nullptr, tab, ntl, offs, tlist, pw, IDIM);
}